// Round 1
// baseline (1182.248 us; speedup 1.0000x reference)
//
#include <hip/hip_runtime.h>
#include <stdint.h>

// BilinearDiscriminator: out = sigmoid( (x @ W^T) @ y^T )
// x: [16384,128] f32, y: [16384,128] f32, W: [128,128] f32, out: [16384,16384] f32
//
// Strategy: fp16 hi/lo split-precision MFMA (3 products: hh + hl + lh, rel err ~2^-21)
// so the 68.7 GFLOP GEMM runs on matrix cores (~2.2 PF) instead of fp32 VALU (157 TF).
// Kernel is HBM-write-bound: 1.074 GB of fp32 output => ~170 us floor at 6.3 TB/s.

typedef unsigned short u16;
typedef _Float16 v8h __attribute__((ext_vector_type(8)));
typedef float v4f __attribute__((ext_vector_type(4)));

#define NROWS 16384
#define DK 128

__device__ inline u16 f2h_bits(float f) {
  _Float16 h = (_Float16)f;
  return __builtin_bit_cast(u16, h);
}
__device__ inline float h2f_bits(u16 b) {
  return (float)__builtin_bit_cast(_Float16, b);
}

// async global->LDS, 16B per lane. LDS dest = wave-uniform base + lane*16 (HW rule).
__device__ inline void gload16(const void* g, void* l) {
  __builtin_amdgcn_global_load_lds(
      (__attribute__((address_space(1))) void*)g,
      (__attribute__((address_space(3))) void*)l,
      16, 0, 0);
}

// fp32 -> fp16 hi + fp16 lo residual split, 4 elems/thread, vectorized.
__global__ void split_kernel(const float* __restrict__ src, u16* __restrict__ hi,
                             u16* __restrict__ lo, int n4) {
  int i = blockIdx.x * blockDim.x + threadIdx.x;
  if (i >= n4) return;
  float4 v = ((const float4*)src)[i];
  float a[4] = {v.x, v.y, v.z, v.w};
  u16 hh[4], ll[4];
#pragma unroll
  for (int j = 0; j < 4; ++j) {
    hh[j] = f2h_bits(a[j]);
    ll[j] = f2h_bits(a[j] - h2f_bits(hh[j]));
  }
  ((ushort4*)hi)[i] = make_ushort4(hh[0], hh[1], hh[2], hh[3]);
  ((ushort4*)lo)[i] = make_ushort4(ll[0], ll[1], ll[2], ll[3]);
}

// Tiled split-precision GEMM:  C[n][m] = sum_k A[n][k]*B[m][k]  (A,B given as fp16 hi/lo)
// MODE 0: A = x (in-place rewrite to xt hi/lo), B = W (128 rows), grid = 128 blocks.
// MODE 1: A = xt, B = y, epilogue sigmoid -> fp32 out, grid = 16384 blocks.
// Tile 128x128, K=128 in two BK=64 chunks. LDS: 4 arrays x 16 KB = 64 KB (2 blocks/CU).
// LDS layout XOR-swizzled (chunk16 ^= row&7): global_load_lds-compatible (no pad) and
// ds_read_b128 fragment reads land at 2-way bank aliasing (free).
template <int MODE>
__global__ __launch_bounds__(256, 2) void gemm_kernel(
    const u16* ah_g, const u16* al_g, const u16* bh_g, const u16* bl_g,
    float* out, u16* xth, u16* xtl) {
  __shared__ __align__(16) u16 sAh[128 * 64];
  __shared__ __align__(16) u16 sAl[128 * 64];
  __shared__ __align__(16) u16 sBh[128 * 64];
  __shared__ __align__(16) u16 sBl[128 * 64];

  const int tid = threadIdx.x;
  const int lane = tid & 63;
  const int w = tid >> 6;       // wave 0..3
  const int quad = lane >> 4;   // 0..3
  const int r = lane & 15;

  int bid = blockIdx.x;
  int tm, tn;
  if (MODE == 0) {
    tm = 0;
    tn = bid;
  } else {
    // 8x8 supertile swizzle: 64 consecutive bids form an 8x8 tile square (L2 locality).
    int super = bid >> 6, within = bid & 63;
    tm = ((super & 15) << 3) | (within & 7);
    tn = ((super >> 4) << 3) | (within >> 3);
  }
  const int arowbase = tn * 128;
  const int browbase = (MODE == 0) ? 0 : tm * 128;

  // wave -> 64x64 quadrant of the 128x128 tile
  const int wn = (w >> 1) * 64;  // n offset
  const int wm = (w & 1) * 64;   // m offset

  v4f acc[4][4] = {};

  // each wave stages one LDS array (16 segments x 1KB)
  const u16* gsrc = (w == 0) ? ah_g : (w == 1) ? al_g : (w == 2) ? bh_g : bl_g;
  u16* larr = (w == 0) ? sAh : (w == 1) ? sAl : (w == 2) ? sBh : sBl;
  const int rowbase = (w < 2) ? arowbase : browbase;

  for (int kc = 0; kc < 2; ++kc) {
    const int kbase = kc * 64;
    if (kc) __syncthreads();  // previous chunk's compute must finish before overwrite
#pragma unroll
    for (int i = 0; i < 16; ++i) {
      int O = i * 1024 + lane * 16;  // byte offset within array
      int row = O >> 7;              // 0..127
      int c = (O >> 4) & 7;          // 16B-chunk within row
      int k8 = c ^ (row & 7);        // XOR swizzle: which real k-chunk lives here
      const u16* g = gsrc + (size_t)(rowbase + row) * DK + kbase + k8 * 8;
      gload16((const void*)g, (void*)((char*)larr + i * 1024));
    }
    __syncthreads();

#pragma unroll
    for (int s = 0; s < 2; ++s) {  // two K=32 MFMA slices per chunk
      v8h afh[4], afl[4], bfh[4], bfl[4];
#pragma unroll
      for (int t = 0; t < 4; ++t) {
        int arow = wn + t * 16 + r;
        int ac = (s * 4 + quad) ^ (arow & 7);
        afh[t] = *(const v8h*)&sAh[arow * 64 + ac * 8];
        afl[t] = *(const v8h*)&sAl[arow * 64 + ac * 8];
        int brow = wm + t * 16 + r;
        int bc = (s * 4 + quad) ^ (brow & 7);
        bfh[t] = *(const v8h*)&sBh[brow * 64 + bc * 8];
        bfl[t] = *(const v8h*)&sBl[brow * 64 + bc * 8];
      }
#pragma unroll
      for (int mt = 0; mt < 4; ++mt)
#pragma unroll
        for (int nt = 0; nt < 4; ++nt) {
          acc[mt][nt] = __builtin_amdgcn_mfma_f32_16x16x32_f16(afh[mt], bfh[nt], acc[mt][nt], 0, 0, 0);
          acc[mt][nt] = __builtin_amdgcn_mfma_f32_16x16x32_f16(afh[mt], bfl[nt], acc[mt][nt], 0, 0, 0);
          acc[mt][nt] = __builtin_amdgcn_mfma_f32_16x16x32_f16(afl[mt], bfh[nt], acc[mt][nt], 0, 0, 0);
        }
    }
  }

  // Epilogue. C/D layout (verified m89/m91): col = lane&15 (m), row = quad*4 + reg (n).
  if (MODE == 0) {
#pragma unroll
    for (int mt = 0; mt < 4; ++mt) {
      int n0 = arowbase + wn + mt * 16 + quad * 4;
#pragma unroll
      for (int nt = 0; nt < 4; ++nt) {
        int d = wm + nt * 16 + r;
#pragma unroll
        for (int v = 0; v < 4; ++v) {
          float val = acc[mt][nt][v];
          u16 h = f2h_bits(val);
          u16 l = f2h_bits(val - h2f_bits(h));
          xth[(size_t)(n0 + v) * DK + d] = h;
          xtl[(size_t)(n0 + v) * DK + d] = l;
        }
      }
    }
  } else {
#pragma unroll
    for (int mt = 0; mt < 4; ++mt) {
#pragma unroll
      for (int v = 0; v < 4; ++v) {
        int n = tn * 128 + wn + mt * 16 + quad * 4 + v;
        size_t rowoff = (size_t)n * NROWS;
#pragma unroll
        for (int nt = 0; nt < 4; ++nt) {
          int m = tm * 128 + wm + nt * 16 + r;
          float sc = acc[mt][nt][v];
          out[rowoff + m] = 1.0f / (1.0f + __expf(-sc));
        }
      }
    }
  }
}

extern "C" void kernel_launch(void* const* d_in, const int* in_sizes, int n_in,
                              void* d_out, int out_size, void* d_ws, size_t ws_size,
                              hipStream_t stream) {
  const float* x = (const float*)d_in[0];
  const float* y = (const float*)d_in[1];
  const float* W = (const float*)d_in[2];
  float* out = (float*)d_out;

  const size_t ND = (size_t)NROWS * DK;  // 2097152
  u16* xh = (u16*)d_ws;                  // 4 MB  (becomes xt_hi after gemm<0>)
  u16* xl = xh + ND;                     // 4 MB  (becomes xt_lo)
  u16* yh = xl + ND;                     // 4 MB
  u16* yl = yh + ND;                     // 4 MB
  u16* Wh = yl + ND;                     // 32 KB
  u16* Wl = Wh + DK * DK;                // 32 KB   total ~16.1 MB of ws

  int n4xy = (int)(ND / 4);
  int n4w = (DK * DK) / 4;
  split_kernel<<<(n4xy + 255) / 256, 256, 0, stream>>>(x, xh, xl, n4xy);
  split_kernel<<<(n4xy + 255) / 256, 256, 0, stream>>>(y, yh, yl, n4xy);
  split_kernel<<<(n4w + 255) / 256, 256, 0, stream>>>(W, Wh, Wl, n4w);

  // xt = x @ W^T  (in-place over xh/xl: each block reads its rows to LDS before writing)
  gemm_kernel<0><<<128, 256, 0, stream>>>(xh, xl, Wh, Wl, out, xh, xl);

  // out = sigmoid(xt @ y^T)
  gemm_kernel<1><<<16384, 256, 0, stream>>>(xh, xl, yh, yl, out, nullptr, nullptr);
}